// Round 23
// baseline (106.787 us; speedup 1.0000x reference)
//
#include <hip/hip_runtime.h>
#include <hip/hip_bf16.h>

#define D 128
#define C 16
#define NBMAX 512     // max buckets
#define VPT 8         // edges per thread in scatter pass (391 blocks: full CU coverage)
#define CAP 8192      // fixed tmp capacity per bucket (expected ~2050, +5 sigma ~2300)

typedef unsigned int uint;
typedef unsigned short ushort;
typedef __attribute__((ext_vector_type(8))) short short8;
typedef __attribute__((ext_vector_type(4))) float f32x4;

// RNE pack of two fp32 -> bf16x2 in a uint (lo = a, hi = b)
__device__ __forceinline__ uint pack_bf16(float a, float b) {
    uint ua = __float_as_uint(a);
    uint ub = __float_as_uint(b);
    ua += 0x7fffu + ((ua >> 16) & 1u);
    ub += 0x7fffu + ((ub >> 16) & 1u);
    return (ua >> 16) | (ub & 0xffff0000u);
}
__device__ __forceinline__ ushort bf1(float a) {
    uint u = __float_as_uint(a);
    u += 0x7fffu + ((u >> 16) & 1u);
    return (ushort)(u >> 16);
}
__device__ __forceinline__ float bf_lo(uint u) { return __uint_as_float(u << 16); }
__device__ __forceinline__ float bf_hi(uint u) { return __uint_as_float(u & 0xffff0000u); }

// ---------------------------------------------------------------- prep
__global__ __launch_bounds__(256) void k_prep(const int* __restrict__ src,
                                              const int* __restrict__ dst,
                                              const float* __restrict__ W0,
                                              const float* __restrict__ W1,
                                              const float* __restrict__ Wc,
                                              ushort* __restrict__ Wt0,
                                              ushort* __restrict__ Wt1,
                                              ushort* __restrict__ Wct,
                                              int* __restrict__ cur,
                                              uint* __restrict__ tmp,
                                              uint* __restrict__ hA,
                                              uint* __restrict__ hB,
                                              int E, int shift, int N) {
    __shared__ int lcnt[NBMAX];
    __shared__ int lbase[NBMAX];
    int tid = threadIdx.x;
    int mask = (1 << shift) - 1;
    lcnt[tid] = 0; lcnt[tid + 256] = 0;
    __syncthreads();
    long e0 = (long)blockIdx.x * (256 * VPT);
    uint ps[VPT]; int pb[VPT];
    #pragma unroll
    for (int t = 0; t < VPT; ++t) {
        long e = e0 + t * 256 + tid;
        if (e < E) {
            int s = src[e], d = dst[e];
            int b = d >> shift;
            pb[t] = b;
            ps[t] = (uint)s | ((uint)(d & mask) << 17);
            atomicAdd(&lcnt[b], 1);
        } else pb[t] = -1;
    }
    __syncthreads();
    for (int b = tid; b < NBMAX; b += 256) {
        int c = lcnt[b];
        lbase[b] = c ? atomicAdd(&cur[b], c) : 0;
    }
    __syncthreads();
    lcnt[tid] = 0; lcnt[tid + 256] = 0;
    __syncthreads();
    #pragma unroll
    for (int t = 0; t < VPT; ++t) {
        if (pb[t] >= 0) {
            int r = atomicAdd(&lcnt[pb[t]], 1);
            int pos = lbase[pb[t]] + r;
            if (pos < CAP)                         // overflow clamp (never hit for this input)
                tmp[(size_t)pb[t] * CAP + pos] = ps[t];
        }
    }

    // ---- fused weight convert (grid-stride) ----
    for (int i = blockIdx.x * 256 + tid; i < D * D; i += gridDim.x * 256) {
        int n = i >> 7, k = i & 127;
        Wt0[i] = bf1(W0[k * D + n]);
        Wt1[i] = bf1(W1[k * D + n]);
    }
    for (int i = blockIdx.x * 256 + tid; i < D * C; i += gridDim.x * 256) {
        int c2 = i >> 7, k = i & 127;
        Wct[i] = bf1(Wc[k * C + c2]);
    }
    // zero pad-target row N of BOTH h tables
    if (blockIdx.x == 0 && tid < 64) {
        hA[(size_t)N * 64 + tid] = 0;
        hB[(size_t)N * 64 + tid] = 0;
    }
}

// ---------------------------------------------------------------- build
// nodeinfo[v] = (batchStart << 8) | nBatches
// Scan over W node-batch-counts done with per-wave shfl_up scans (1 sync).
__global__ __launch_bounds__(256) void k_build(const uint* __restrict__ tmp,
                                               const int* __restrict__ cur,
                                               const int* __restrict__ x,
                                               const float* __restrict__ emb,
                                               uint* __restrict__ nodeinfo,
                                               float* __restrict__ dinv,
                                               int* __restrict__ col,
                                               uint* __restrict__ h16,
                                               int N, int shift, int NB) {
    __shared__ int   lc[256];
    __shared__ int   lrow[256];
    __shared__ int   lcur[256];
    __shared__ float lfd[256];
    __shared__ int   wtot[4];
    int b = blockIdx.x, tid = threadIdx.x;
    int lane = tid & 63, wvq = tid >> 6;
    int W = 1 << shift;          // 128 for this problem
    if (tid < W) lc[tid] = 0;
    __syncthreads();
    int cnt = min(cur[b], CAP);
    const uint* bt = tmp + (size_t)b * CAP;
    for (int i = tid; i < cnt; i += 256)
        atomicAdd(&lc[bt[i] >> 17], 1);
    __syncthreads();
    int v0 = (b << shift) + tid;
    int degt = 0, nb8 = 0;
    if (tid < W) {
        degt = (v0 < N) ? lc[tid] + 1 : 0;        // +1 self-loop
        nb8  = (degt + 7) >> 3;                   // 8-slot batches
    }
    // inclusive scan of nb8 over the W leading threads: shfl within wave + wave totals
    int val = (tid < W) ? nb8 : 0;
    #pragma unroll
    for (int d2 = 1; d2 < 64; d2 <<= 1) {
        int t = __shfl_up(val, d2);
        if (lane >= d2) val += t;
    }
    if (lane == 63) wtot[wvq] = val;
    __syncthreads();
    int addp = 0;
    for (int q = 0; q < wvq; ++q) addp += wtot[q];
    val += addp;                                  // inclusive scan across block

    int bstart_base = b * (CAP / 8 + W);                // region start, batch units
    int slot0 = 0;
    if (tid < W) {
        int bstart = bstart_base + val - nb8;           // exclusive scan
        slot0 = bstart << 3;
        float dv = rsqrtf((float)degt);
        lrow[tid] = slot0;
        lcur[tid] = 1;                                  // slot 0 = self-loop
        lfd[tid]  = dv;
        if (v0 < N) {
            nodeinfo[v0] = ((uint)bstart << 8) | (uint)nb8;
            dinv[v0] = dv;
            col[slot0] = v0;
        }
    }
    __syncthreads();
    for (int i = tid; i < cnt; i += 256) {
        uint u = bt[i];
        int off = (int)(u >> 17);
        int r = atomicAdd(&lcur[off], 1);
        col[lrow[off] + r] = (int)(u & 0x1FFFFu);
    }
    __syncthreads();
    // pad slots -> zero-row N
    if (tid < W && v0 < N) {
        for (int i = degt; i < (nb8 << 3); ++i) col[slot0 + i] = N;
    }
    // ---- fused embed ----
    for (int idx = tid; idx < W * 16; idx += 256) {
        int row = idx >> 4;
        int j8  = idx & 15;
        int v = (b << shift) + row;
        if (v >= N) continue;
        float dv = lfd[row];
        int xr = x[v];
        const float4* e4 = (const float4*)(emb + (size_t)xr * D + j8 * 8);
        float4 a = e4[0], bb = e4[1];
        uint4 o;
        o.x = pack_bf16(a.x * dv, a.y * dv);
        o.y = pack_bf16(a.z * dv, a.w * dv);
        o.z = pack_bf16(bb.x * dv, bb.y * dv);
        o.w = pack_bf16(bb.z * dv, bb.w * dv);
        ((uint4*)(h16 + (size_t)v * 64))[j8] = o;
    }
}

// gather-issue helper: NLOAD consecutive row-gathers issued back-to-back
template<int NLOAD>
__device__ __forceinline__ void gather_acc(const uint* __restrict__ hin,
                                           const int* __restrict__ col,
                                           int e, int lane, float& ax, float& ay) {
    int c[NLOAD]; uint u[NLOAD];
    #pragma unroll
    for (int t = 0; t < NLOAD; ++t) c[t] = __builtin_amdgcn_readfirstlane(col[e + t]);
    #pragma unroll
    for (int t = 0; t < NLOAD; ++t) u[t] = hin[(size_t)c[t] * 64 + lane];
    #pragma unroll
    for (int t = 0; t < NLOAD; ++t) { ax += bf_lo(u[t]); ay += bf_hi(u[t]); }
}

// ---------------------------------------------------------------- fused agg + MFMA GEMM
// Block = 16 nodes, 256 threads (4 waves), 8 blocks/CU (32 waves/CU).
template<bool FUSE>
__global__ __launch_bounds__(256, 8) void k_fused(const uint* __restrict__ hin,
                                                  const uint* __restrict__ nodeinfo,
                                                  const int* __restrict__ col,
                                                  const float* __restrict__ dinv,
                                                  const ushort* __restrict__ Wt,   // bf16 [128][128] (n-major)
                                                  const float* __restrict__ b,
                                                  uint* __restrict__ hout16,
                                                  const ushort* __restrict__ Wct,  // bf16 [16][128]
                                                  const float* __restrict__ bc,
                                                  float* __restrict__ outf, int N) {
    __shared__ __align__(16) ushort T[16][136];    // +8 pad
    __shared__ int wptr;
    int tid  = threadIdx.x;
    int wv = tid >> 6, lane = tid & 63;
    long tile0 = (long)blockIdx.x * 16;

    if (tid == 0) wptr = 0;
    __syncthreads();

    // ---- phase 1: work-stealing aggregation, whole-node gather issue ----
    for (;;) {
        int i = 0;
        if (lane == 0) i = atomicAdd(&wptr, 1);
        i = __builtin_amdgcn_readfirstlane(i);
        if (i >= 16) break;
        long v = tile0 + i;
        float ax = 0.f, ay = 0.f;
        if (v < N) {
            uint info = (uint)__builtin_amdgcn_readfirstlane((int)nodeinfo[v]);
            int e   = (int)(info >> 8) << 3;
            int nb8 = (int)(info & 255u);
            if (nb8 == 3) {                       // dominant case: deg 9..24
                gather_acc<24>(hin, col, e, lane, ax, ay);
            } else if (nb8 == 2) {
                gather_acc<16>(hin, col, e, lane, ax, ay);
            } else if (nb8 == 1) {
                gather_acc<8>(hin, col, e, lane, ax, ay);
            } else {                              // rare: deg >= 25
                int k2 = 0;
                for (; k2 + 2 <= nb8; k2 += 2, e += 16)
                    gather_acc<16>(hin, col, e, lane, ax, ay);
                if (k2 < nb8)
                    gather_acc<8>(hin, col, e, lane, ax, ay);
            }
            float dv = dinv[v];
            ax *= dv; ay *= dv;
        }
        *(uint*)&T[i][lane * 2] = pack_bf16(ax, ay);
    }
    __syncthreads();

    // ---- phase 2: MFMA GEMM from LDS A-frags ----
    int nt0 = wv * 2;             // nt pair: 4 waves cover nt 0..7
    int c0 = lane & 15, g = lane >> 4;

    short8 a[4];
    #pragma unroll
    for (int kk = 0; kk < 4; ++kk)
        a[kk] = *(const short8*)((const char*)&T[c0][0] + kk * 64 + g * 16);
    __syncthreads();              // all A-frags read before T is overwritten

    float dsc[4];
    #pragma unroll
    for (int j = 0; j < 4; ++j) {
        long r = tile0 + g * 4 + j; if (r >= N) r = N - 1;
        dsc[j] = FUSE ? 1.f : dinv[r];
    }

    #pragma unroll
    for (int nt = nt0; nt < nt0 + 2; ++nt) {
        float bias = b[nt * 16 + c0];
        f32x4 acc = {bias, bias, bias, bias};
        const ushort* wb = Wt + (size_t)(nt * 16 + c0) * D + g * 8;
        #pragma unroll
        for (int kk = 0; kk < 4; ++kk) {
            short8 bf = *(const short8*)(wb + kk * 32);
            acc = __builtin_amdgcn_mfma_f32_16x16x32_bf16(a[kk], bf, acc, 0, 0, 0);
        }
        #pragma unroll
        for (int j = 0; j < 4; ++j)
            T[g * 4 + j][nt * 16 + c0] = bf1(fmaxf(acc[j], 0.f) * dsc[j]);
    }
    __syncthreads();

    if (!FUSE) {
        // coalesced table store: thread t -> 16 B of row (t>>4); 256 threads = 16 rows
        int r = tid >> 4, q = tid & 15;
        long grow = tile0 + r;
        if (grow < N) {
            *(uint4*)((char*)(hout16 + grow * 64) + q * 16) =
                *(const uint4*)((const char*)&T[r][0] + q * 16);
        }
    } else if (wv == 0) {
        // classifier: wave 0 owns the 16-row tile
        float biasc = bc[c0];
        f32x4 acc2 = {biasc, biasc, biasc, biasc};
        #pragma unroll
        for (int kk = 0; kk < 4; ++kk) {
            short8 ta = *(const short8*)((const char*)&T[c0][0] + kk * 64 + g * 16);
            short8 wc = *(const short8*)(Wct + (size_t)c0 * D + kk * 32 + g * 8);
            acc2 = __builtin_amdgcn_mfma_f32_16x16x32_bf16(ta, wc, acc2, 0, 0, 0);
        }
        #pragma unroll
        for (int j = 0; j < 4; ++j) {
            long grow = tile0 + g * 4 + j;
            if (grow < N) outf[grow * C + c0] = acc2[j];
        }
    }
}

// ---------------------------------------------------------------- launch

extern "C" void kernel_launch(void* const* d_in, const int* in_sizes, int n_in,
                              void* d_out, int out_size, void* d_ws, size_t ws_size,
                              hipStream_t stream) {
    const int*   x    = (const int*)  d_in[0];
    const int*   ei   = (const int*)  d_in[1];   // [2,E]: first E = src, next E = dst
    const float* emb  = (const float*)d_in[2];
    const float* W0   = (const float*)d_in[3];
    const float* b0   = (const float*)d_in[4];
    const float* W1   = (const float*)d_in[5];
    const float* b1   = (const float*)d_in[6];
    const float* Wc   = (const float*)d_in[7];
    const float* bc   = (const float*)d_in[8];
    float* out = (float*)d_out;

    const int N  = in_sizes[0];
    const int E  = in_sizes[1] / 2;

    const int* src = ei;
    const int* dst = ei + E;

    // bucket shift: width 2^shift, NB <= NBMAX  (N=50000 -> shift 7, NB=391)
    int shift = 7;
    while (((N + (1 << shift) - 1) >> shift) > NBMAX) shift++;
    const int NB = (N + (1 << shift) - 1) >> shift;
    const int W  = 1 << shift;

    // padded col capacity: NB regions of (CAP/8 + W) batches
    const size_t colCap = (size_t)NB * (CAP / 8 + W) * 8 + 64;

    char* p = (char*)d_ws;
    auto take = [&](size_t bytes) { char* q = p; p += (bytes + 255) & ~(size_t)255; return q; };
    uint*   nodeinfo = (uint*) take((size_t)N * 4);
    float*  dinv    = (float*) take((size_t)N * 4);
    int*    cur     = (int*)   take((size_t)NBMAX * 4);
    uint*   tmp     = (uint*)  take((size_t)NB * CAP * 4);
    int*    col     = (int*)   take(colCap * 4);
    ushort* Wt0     = (ushort*)take((size_t)D * D * 2);
    ushort* Wt1     = (ushort*)take((size_t)D * D * 2);
    ushort* Wct     = (ushort*)take((size_t)D * C * 2);
    uint*   hA16    = (uint*)  take((size_t)(N + 1) * 64 * 4);  // +1: zero pad row
    uint*   hB16    = (uint*)  take((size_t)(N + 1) * 64 * 4);

    const int BS = 256;
    const int EB = (int)(((long)E + 256 * VPT - 1) / (256 * VPT));
    const int NT16 = (N + 15) / 16;

    hipMemsetAsync(cur, 0, NBMAX * 4, stream);
    k_prep <<<EB, BS, 0, stream>>>(src, dst, W0, W1, Wc, Wt0, Wt1, Wct,
                                   cur, tmp, hA16, hB16, E, shift, N);
    k_build<<<NB, BS, 0, stream>>>(tmp, cur, x, emb, nodeinfo, dinv, col, hA16,
                                   N, shift, NB);

    // layer 0: hB16 = bf16( relu((A*hA16)@W0 + b0) * dinv )   [fused agg+gemm]
    k_fused<false><<<NT16, 256, 0, stream>>>(hA16, nodeinfo, col, dinv, Wt0, b0,
                                             hB16, nullptr, nullptr, nullptr, N);
    // layer 1 + classifier: out = relu((A*hB16)@W1 + b1) @ Wc + bc
    k_fused<true><<<NT16, 256, 0, stream>>>(hB16, nodeinfo, col, dinv, Wt1, b1,
                                            nullptr, Wct, bc, out, N);
}

// Round 24
// 105.430 us; speedup vs baseline: 1.0129x; 1.0129x over previous
//
#include <hip/hip_runtime.h>
#include <hip/hip_bf16.h>

#define D 128
#define C 16
#define NBMAX 512     // max buckets
#define VPT 16        // edges per thread in scatter pass
#define CAP 8192      // fixed tmp capacity per bucket (expected ~2050, +5 sigma ~2300)

typedef unsigned int uint;
typedef unsigned short ushort;
typedef __attribute__((ext_vector_type(8))) short short8;
typedef __attribute__((ext_vector_type(4))) float f32x4;

// RNE pack of two fp32 -> bf16x2 in a uint (lo = a, hi = b)
__device__ __forceinline__ uint pack_bf16(float a, float b) {
    uint ua = __float_as_uint(a);
    uint ub = __float_as_uint(b);
    ua += 0x7fffu + ((ua >> 16) & 1u);
    ub += 0x7fffu + ((ub >> 16) & 1u);
    return (ua >> 16) | (ub & 0xffff0000u);
}
__device__ __forceinline__ ushort bf1(float a) {
    uint u = __float_as_uint(a);
    u += 0x7fffu + ((u >> 16) & 1u);
    return (ushort)(u >> 16);
}
__device__ __forceinline__ float bf_lo(uint u) { return __uint_as_float(u << 16); }
__device__ __forceinline__ float bf_hi(uint u) { return __uint_as_float(u & 0xffff0000u); }

// ---------------------------------------------------------------- prep
__global__ __launch_bounds__(256) void k_prep(const int* __restrict__ src,
                                              const int* __restrict__ dst,
                                              const float* __restrict__ W0,
                                              const float* __restrict__ W1,
                                              const float* __restrict__ Wc,
                                              ushort* __restrict__ Wt0,
                                              ushort* __restrict__ Wt1,
                                              ushort* __restrict__ Wct,
                                              int* __restrict__ cur,
                                              uint* __restrict__ tmp,
                                              uint* __restrict__ hA,
                                              uint* __restrict__ hB,
                                              int E, int shift, int N) {
    __shared__ int lcnt[NBMAX];
    __shared__ int lbase[NBMAX];
    int tid = threadIdx.x;
    int mask = (1 << shift) - 1;
    lcnt[tid] = 0; lcnt[tid + 256] = 0;
    __syncthreads();
    long e0 = (long)blockIdx.x * (256 * VPT);
    uint ps[VPT]; int pb[VPT];
    #pragma unroll
    for (int t = 0; t < VPT; ++t) {
        long e = e0 + t * 256 + tid;
        if (e < E) {
            int s = src[e], d = dst[e];
            int b = d >> shift;
            pb[t] = b;
            ps[t] = (uint)s | ((uint)(d & mask) << 17);
            atomicAdd(&lcnt[b], 1);
        } else pb[t] = -1;
    }
    __syncthreads();
    for (int b = tid; b < NBMAX; b += 256) {
        int c = lcnt[b];
        lbase[b] = c ? atomicAdd(&cur[b], c) : 0;
    }
    __syncthreads();
    lcnt[tid] = 0; lcnt[tid + 256] = 0;
    __syncthreads();
    #pragma unroll
    for (int t = 0; t < VPT; ++t) {
        if (pb[t] >= 0) {
            int r = atomicAdd(&lcnt[pb[t]], 1);
            int pos = lbase[pb[t]] + r;
            if (pos < CAP)                         // overflow clamp (never hit for this input)
                tmp[(size_t)pb[t] * CAP + pos] = ps[t];
        }
    }

    // ---- fused weight convert (grid-stride) ----
    for (int i = blockIdx.x * 256 + tid; i < D * D; i += gridDim.x * 256) {
        int n = i >> 7, k = i & 127;
        Wt0[i] = bf1(W0[k * D + n]);
        Wt1[i] = bf1(W1[k * D + n]);
    }
    for (int i = blockIdx.x * 256 + tid; i < D * C; i += gridDim.x * 256) {
        int c2 = i >> 7, k = i & 127;
        Wct[i] = bf1(Wc[k * C + c2]);
    }
    // zero pad-target row N of BOTH h tables
    if (blockIdx.x == 0 && tid < 64) {
        hA[(size_t)N * 64 + tid] = 0;
        hB[(size_t)N * 64 + tid] = 0;
    }
}

// ---------------------------------------------------------------- build
// nodeinfo[v] = (batchStart << 8) | nBatches
__global__ __launch_bounds__(256) void k_build(const uint* __restrict__ tmp,
                                               const int* __restrict__ cur,
                                               const int* __restrict__ x,
                                               const float* __restrict__ emb,
                                               uint* __restrict__ nodeinfo,
                                               float* __restrict__ dinv,
                                               int* __restrict__ col,
                                               uint* __restrict__ h16,
                                               int N, int shift, int NB) {
    __shared__ int   lc[256];
    __shared__ int   lrow[256];
    __shared__ int   lcur[256];
    __shared__ float lfd[256];
    int b = blockIdx.x, tid = threadIdx.x;
    int W = 1 << shift;          // 128 for this problem
    if (tid < W) lc[tid] = 0;
    __syncthreads();
    int cnt = min(cur[b], CAP);
    const uint* bt = tmp + (size_t)b * CAP;
    for (int i = tid; i < cnt; i += 256)
        atomicAdd(&lc[bt[i] >> 17], 1);
    __syncthreads();
    int v0 = (b << shift) + tid;
    int degt = 0, nb8 = 0;
    if (tid < W) {
        degt = (v0 < N) ? lc[tid] + 1 : 0;        // +1 self-loop
        nb8  = (degt + 7) >> 3;                   // 8-slot batches
        lrow[tid] = nb8;
    }
    __syncthreads();
    for (int off = 1; off < W; off <<= 1) {
        int t = 0;
        if (tid < W && tid >= off) t = lrow[tid - off];
        __syncthreads();
        if (tid < W) lrow[tid] += t;
        __syncthreads();
    }
    int bstart_base = b * (CAP / 8 + W);                // region start, batch units
    int slot0 = 0;
    if (tid < W) {
        int bstart = bstart_base + lrow[tid] - nb8;     // exclusive scan
        slot0 = bstart << 3;
        float dv = rsqrtf((float)degt);
        lrow[tid] = slot0;
        lcur[tid] = 1;                                  // slot 0 = self-loop
        lfd[tid]  = dv;
        if (v0 < N) {
            nodeinfo[v0] = ((uint)bstart << 8) | (uint)nb8;
            dinv[v0] = dv;
            col[slot0] = v0;
        }
    }
    __syncthreads();
    for (int i = tid; i < cnt; i += 256) {
        uint u = bt[i];
        int off = (int)(u >> 17);
        int r = atomicAdd(&lcur[off], 1);
        col[lrow[off] + r] = (int)(u & 0x1FFFFu);
    }
    __syncthreads();
    // pad slots -> zero-row N
    if (tid < W && v0 < N) {
        for (int i = degt; i < (nb8 << 3); ++i) col[slot0 + i] = N;
    }
    // ---- fused embed ----
    for (int idx = tid; idx < W * 16; idx += 256) {
        int row = idx >> 4;
        int j8  = idx & 15;
        int v = (b << shift) + row;
        if (v >= N) continue;
        float dv = lfd[row];
        int xr = x[v];
        const float4* e4 = (const float4*)(emb + (size_t)xr * D + j8 * 8);
        float4 a = e4[0], bb = e4[1];
        uint4 o;
        o.x = pack_bf16(a.x * dv, a.y * dv);
        o.y = pack_bf16(a.z * dv, a.w * dv);
        o.z = pack_bf16(bb.x * dv, bb.y * dv);
        o.w = pack_bf16(bb.z * dv, bb.w * dv);
        ((uint4*)(h16 + (size_t)v * 64))[j8] = o;
    }
}

// gather-issue helper: NLOAD consecutive row-gathers issued back-to-back
// (cols via consecutive scalar loads; address = scalar base + lane offset)
template<int NLOAD>
__device__ __forceinline__ void gather_acc(const uint* __restrict__ hin,
                                           const int* __restrict__ col,
                                           int e, int lane, float& ax, float& ay) {
    int c[NLOAD]; uint u[NLOAD];
    #pragma unroll
    for (int t = 0; t < NLOAD; ++t) c[t] = __builtin_amdgcn_readfirstlane(col[e + t]);
    #pragma unroll
    for (int t = 0; t < NLOAD; ++t) u[t] = hin[(size_t)c[t] * 64 + lane];
    #pragma unroll
    for (int t = 0; t < NLOAD; ++t) { ax += bf_lo(u[t]); ay += bf_hi(u[t]); }
}

// ---------------------------------------------------------------- fused agg + MFMA GEMM
// Block = 16 nodes, 256 threads (4 waves), 8 blocks/CU (32 waves/CU).
// Phase 1: work-stealing node-per-wave aggregation. The node's ENTIRE gather
// set is issued at once via nb8-specialized straight-line paths (8/16/24
// loads in flight; nb8 is wave-uniform so branches don't diverge).
// Phase 2: MFMA GEMM from LDS; classifier (FUSE) = wave 0.
template<bool FUSE>
__global__ __launch_bounds__(256, 8) void k_fused(const uint* __restrict__ hin,
                                                  const uint* __restrict__ nodeinfo,
                                                  const int* __restrict__ col,
                                                  const float* __restrict__ dinv,
                                                  const ushort* __restrict__ Wt,   // bf16 [128][128] (n-major)
                                                  const float* __restrict__ b,
                                                  uint* __restrict__ hout16,
                                                  const ushort* __restrict__ Wct,  // bf16 [16][128]
                                                  const float* __restrict__ bc,
                                                  float* __restrict__ outf, int N) {
    __shared__ __align__(16) ushort T[16][136];    // +8 pad
    __shared__ int wptr;
    int tid  = threadIdx.x;
    int wv = tid >> 6, lane = tid & 63;
    long tile0 = (long)blockIdx.x * 16;

    if (tid == 0) wptr = 0;
    __syncthreads();

    // ---- phase 1: work-stealing aggregation, whole-node gather issue ----
    for (;;) {
        int i = 0;
        if (lane == 0) i = atomicAdd(&wptr, 1);
        i = __builtin_amdgcn_readfirstlane(i);
        if (i >= 16) break;
        long v = tile0 + i;
        float ax = 0.f, ay = 0.f;
        if (v < N) {
            uint info = (uint)__builtin_amdgcn_readfirstlane((int)nodeinfo[v]);
            int e   = (int)(info >> 8) << 3;
            int nb8 = (int)(info & 255u);
            if (nb8 == 3) {                       // dominant case: deg 9..24
                gather_acc<24>(hin, col, e, lane, ax, ay);
            } else if (nb8 == 2) {
                gather_acc<16>(hin, col, e, lane, ax, ay);
            } else if (nb8 == 1) {
                gather_acc<8>(hin, col, e, lane, ax, ay);
            } else {                              // rare: deg >= 25
                int k2 = 0;
                for (; k2 + 2 <= nb8; k2 += 2, e += 16)
                    gather_acc<16>(hin, col, e, lane, ax, ay);
                if (k2 < nb8)
                    gather_acc<8>(hin, col, e, lane, ax, ay);
            }
            float dv = dinv[v];
            ax *= dv; ay *= dv;
        }
        *(uint*)&T[i][lane * 2] = pack_bf16(ax, ay);
    }
    __syncthreads();

    // ---- phase 2: MFMA GEMM from LDS A-frags ----
    int nt0 = wv * 2;             // nt pair: 4 waves cover nt 0..7
    int c0 = lane & 15, g = lane >> 4;

    short8 a[4];
    #pragma unroll
    for (int kk = 0; kk < 4; ++kk)
        a[kk] = *(const short8*)((const char*)&T[c0][0] + kk * 64 + g * 16);
    __syncthreads();              // all A-frags read before T is overwritten

    float dsc[4];
    #pragma unroll
    for (int j = 0; j < 4; ++j) {
        long r = tile0 + g * 4 + j; if (r >= N) r = N - 1;
        dsc[j] = FUSE ? 1.f : dinv[r];
    }

    #pragma unroll
    for (int nt = nt0; nt < nt0 + 2; ++nt) {
        float bias = b[nt * 16 + c0];
        f32x4 acc = {bias, bias, bias, bias};
        const ushort* wb = Wt + (size_t)(nt * 16 + c0) * D + g * 8;
        #pragma unroll
        for (int kk = 0; kk < 4; ++kk) {
            short8 bf = *(const short8*)(wb + kk * 32);
            acc = __builtin_amdgcn_mfma_f32_16x16x32_bf16(a[kk], bf, acc, 0, 0, 0);
        }
        #pragma unroll
        for (int j = 0; j < 4; ++j)
            T[g * 4 + j][nt * 16 + c0] = bf1(fmaxf(acc[j], 0.f) * dsc[j]);
    }
    __syncthreads();

    if (!FUSE) {
        // coalesced table store: thread t -> 16 B of row (t>>4); 256 threads = 16 rows
        int r = tid >> 4, q = tid & 15;
        long grow = tile0 + r;
        if (grow < N) {
            *(uint4*)((char*)(hout16 + grow * 64) + q * 16) =
                *(const uint4*)((const char*)&T[r][0] + q * 16);
        }
    } else if (wv == 0) {
        // classifier: wave 0 owns the 16-row tile
        float biasc = bc[c0];
        f32x4 acc2 = {biasc, biasc, biasc, biasc};
        #pragma unroll
        for (int kk = 0; kk < 4; ++kk) {
            short8 ta = *(const short8*)((const char*)&T[c0][0] + kk * 64 + g * 16);
            short8 wc = *(const short8*)(Wct + (size_t)c0 * D + kk * 32 + g * 8);
            acc2 = __builtin_amdgcn_mfma_f32_16x16x32_bf16(ta, wc, acc2, 0, 0, 0);
        }
        #pragma unroll
        for (int j = 0; j < 4; ++j) {
            long grow = tile0 + g * 4 + j;
            if (grow < N) outf[grow * C + c0] = acc2[j];
        }
    }
}

// ---------------------------------------------------------------- launch

extern "C" void kernel_launch(void* const* d_in, const int* in_sizes, int n_in,
                              void* d_out, int out_size, void* d_ws, size_t ws_size,
                              hipStream_t stream) {
    const int*   x    = (const int*)  d_in[0];
    const int*   ei   = (const int*)  d_in[1];   // [2,E]: first E = src, next E = dst
    const float* emb  = (const float*)d_in[2];
    const float* W0   = (const float*)d_in[3];
    const float* b0   = (const float*)d_in[4];
    const float* W1   = (const float*)d_in[5];
    const float* b1   = (const float*)d_in[6];
    const float* Wc   = (const float*)d_in[7];
    const float* bc   = (const float*)d_in[8];
    float* out = (float*)d_out;

    const int N  = in_sizes[0];
    const int E  = in_sizes[1] / 2;

    const int* src = ei;
    const int* dst = ei + E;

    // bucket shift: width 2^shift, NB <= NBMAX  (N=50000 -> shift 7, NB=391)
    int shift = 7;
    while (((N + (1 << shift) - 1) >> shift) > NBMAX) shift++;
    const int NB = (N + (1 << shift) - 1) >> shift;
    const int W  = 1 << shift;

    // padded col capacity: NB regions of (CAP/8 + W) batches
    const size_t colCap = (size_t)NB * (CAP / 8 + W) * 8 + 64;

    char* p = (char*)d_ws;
    auto take = [&](size_t bytes) { char* q = p; p += (bytes + 255) & ~(size_t)255; return q; };
    uint*   nodeinfo = (uint*) take((size_t)N * 4);
    float*  dinv    = (float*) take((size_t)N * 4);
    int*    cur     = (int*)   take((size_t)NBMAX * 4);
    uint*   tmp     = (uint*)  take((size_t)NB * CAP * 4);
    int*    col     = (int*)   take(colCap * 4);
    ushort* Wt0     = (ushort*)take((size_t)D * D * 2);
    ushort* Wt1     = (ushort*)take((size_t)D * D * 2);
    ushort* Wct     = (ushort*)take((size_t)D * C * 2);
    uint*   hA16    = (uint*)  take((size_t)(N + 1) * 64 * 4);  // +1: zero pad row
    uint*   hB16    = (uint*)  take((size_t)(N + 1) * 64 * 4);

    const int BS = 256;
    const int EB = (int)(((long)E + 256 * VPT - 1) / (256 * VPT));
    const int NT16 = (N + 15) / 16;

    hipMemsetAsync(cur, 0, NBMAX * 4, stream);
    k_prep <<<EB, BS, 0, stream>>>(src, dst, W0, W1, Wc, Wt0, Wt1, Wct,
                                   cur, tmp, hA16, hB16, E, shift, N);
    k_build<<<NB, BS, 0, stream>>>(tmp, cur, x, emb, nodeinfo, dinv, col, hA16,
                                   N, shift, NB);

    // layer 0: hB16 = bf16( relu((A*hA16)@W0 + b0) * dinv )   [fused agg+gemm]
    k_fused<false><<<NT16, 256, 0, stream>>>(hA16, nodeinfo, col, dinv, Wt0, b0,
                                             hB16, nullptr, nullptr, nullptr, N);
    // layer 1 + classifier: out = relu((A*hB16)@W1 + b1) @ Wc + bc
    k_fused<true><<<NT16, 256, 0, stream>>>(hB16, nodeinfo, col, dinv, Wt1, b1,
                                            nullptr, Wct, bc, out, N);
}